// Round 14
// baseline (95.809 us; speedup 1.0000x reference)
//
#include <hip/hip_runtime.h>
#include <math.h>

#define D100 100
#define NE 50000
#define BATCH 16
#define EPS_F 1e-5f
#define TPT 782              // 64-row tiles per tensor (782*64 = 50048, zero-padded)
#define TPB2 4               // tiles per gram block
#define NBG 196              // gram blocks per tensor (proven-fast width)
#define QCI 20               // e-rows per qf chunk
#define QCB 5                // chunks (100/QCI)
#define QNJ 1664             // padded column count
#define SLICES 16
#define SEG3 13              // ceil(NBG/SLICES)
#define K1B 157              // k1-direct ef-blocks per tensor

typedef __attribute__((ext_vector_type(8))) short short8;
typedef __attribute__((ext_vector_type(16))) float float16;
typedef unsigned short u16;
typedef unsigned int u32;

__device__ __forceinline__ float bf2f(u16 v) {
  return __uint_as_float(((u32)v) << 16);
}
__device__ __forceinline__ float f4get(const float4& v, int j) {
  switch (j) { case 0: return v.x; case 1: return v.y; case 2: return v.z; default: return v.w; }
}
__device__ __forceinline__ u32 cvt_pk_bf16(float lo, float hi) {
  u32 val;
  asm volatile("v_cvt_pk_bf16_f32 %0, %1, %2" : "=v"(val) : "v"(lo), "v"(hi));
  return val;
}

#define K2F_LOAD(tile)                                          \
    { int n0 = (tile) * 64;                                     \
      _Pragma("unroll")                                         \
      for (int s = 0; s < 4; s++) {                             \
        int i = s * 256 + tid;                                  \
        float4 a = make_float4(0.f, 0.f, 0.f, 0.f);             \
        float4 b = make_float4(0.f, 0.f, 0.f, 0.f);             \
        if (i < 800) {                                          \
          int p = i / 25, e4 = i - p * 25;                      \
          int n = n0 + 2 * p;                                   \
          if (n < NE)     a = E4[(long)n * 25 + e4];            \
          if (n + 1 < NE) b = E4[(long)(n + 1) * 25 + e4];      \
        }                                                       \
        st0[s] = a; st1[s] = b;                                 \
      } }

// XOR-swizzled write: u32 offset within each (rb,ncl) 256-u32 region is
// (slot*4 + elem2) ^ ((rb&3)<<2).  Spreads the 13-way bank aliasing to ~4-way.
// Read side applies the SAME xor (bits 2-3 only -> 16B slots stay contiguous).
#define K2F_WRITE()                                             \
    { _Pragma("unroll")                                         \
      for (int s = 0; s < 4; s++) {                             \
        int i = s * 256 + tid;                                  \
        if (i < 800) {                                          \
          int p = i / 25, e4 = i - p * 25;                      \
          int ncl = p >> 3, half = (p >> 2) & 1, elem2 = p & 3; \
          _Pragma("unroll")                                     \
          for (int j = 0; j < 4; j++) {                         \
            int e = e4 * 4 + j;                                 \
            int rb = e >> 5;                                    \
            int slot = (e & 31) + 32 * half;                    \
            u32 val = cvt_pk_bf16(f4get(st0[s], j), f4get(st1[s], j)); \
            FR32[rb * 1024 + ncl * 256 + (((slot << 2) + elem2) ^ (rb << 2))] = val; \
          } } } }

// ---------------------------------------------------------------------------
// L1: [k2f MFMA gram, 392 blocks] ∥ [k1-direct Wm build, 314 blocks]
__global__ __launch_bounds__(256) void kA(const float* __restrict__ W_re,
                                          const float* __restrict__ W_im,
                                          const float* __restrict__ R2,
                                          const int* __restrict__ r_idx,
                                          const float* __restrict__ E_a,
                                          const float* __restrict__ E_b,
                                          float* __restrict__ Wm,
                                          float* __restrict__ Gp,
                                          float* __restrict__ CSp) {
  __shared__ union {
    u32 fr32[4096];                                            // gram tile (16 KB)
    struct { float r2s[16][100]; float red[4][64][17]; } k1;   // 23.8 KB
  } sm;
  const int bid = blockIdx.x, tid = threadIdx.x;

  if (bid < 2 * NBG) {
    // ---------------- k2f: fused transpose+cast+MFMA Gram ----------------
    const int t = bid / NBG, bx = bid - t * NBG;
    const float4* E4 = (const float4*)(t ? E_b : E_a);
    u32* FR32 = sm.fr32;
    const int wave = tid >> 6, lane = tid & 63, l31 = lane & 31;

    for (int i = tid; i < 4096; i += 256) FR32[i] = 0;   // rows e>=100 stay 0

    const int ti0 = bx * TPB2;
    const int nt = min(ti0 + TPB2, TPT) - ti0;

    float16 acc0, acc1, acc2, acc3;
#pragma unroll 16
    for (int r = 0; r < 16; r++) { acc0[r] = 0.f; acc1[r] = 0.f; acc2[r] = 0.f; acc3[r] = 0.f; }
    float cs = 0.f;
    float4 st0[4], st1[4];

    // per-lane swizzled read base (within a region): (lane*4) ^ (rb<<2)
    const int lx = lane << 2;

    __syncthreads();
    K2F_LOAD(ti0);
    K2F_WRITE();
    __syncthreads();

    for (int tt = 0; tt < nt; tt++) {
      if (tt + 1 < nt) K2F_LOAD(ti0 + tt + 1);
#pragma unroll
      for (int ncl = 0; ncl < 4; ncl++) {
        const u32* reg = FR32 + ncl * 256;
        short8 f0 = *(const short8*)(reg + 0 * 1024 + (lx ^ 0));
        short8 f1 = *(const short8*)(reg + 1 * 1024 + (lx ^ 4));
        short8 f2 = *(const short8*)(reg + 2 * 1024 + (lx ^ 8));
        short8 f3 = *(const short8*)(reg + 3 * 1024 + (lx ^ 12));
        short8 av = *(const short8*)(reg + wave * 1024 + (lx ^ (wave << 2)));
        acc0 = __builtin_amdgcn_mfma_f32_32x32x16_bf16(av, f0, acc0, 0, 0, 0);
        acc1 = __builtin_amdgcn_mfma_f32_32x32x16_bf16(av, f1, acc1, 0, 0, 0);
        acc2 = __builtin_amdgcn_mfma_f32_32x32x16_bf16(av, f2, acc2, 0, 0, 0);
        acc3 = __builtin_amdgcn_mfma_f32_32x32x16_bf16(av, f3, acc3, 0, 0, 0);
#pragma unroll
        for (int j = 0; j < 8; j++) cs += bf2f((u16)av[j]);
      }
      __syncthreads();
      if (tt + 1 < nt) {
        K2F_WRITE();
        __syncthreads();
      }
    }

    float* gp = Gp + ((long)t * NBG + bx) * 10000;
#pragma unroll 16
    for (int r = 0; r < 16; r++) {
      int m = (r & 3) + 8 * (r >> 2) + 4 * (lane >> 5);   // verified C/D mapping
      int e = wave * 32 + m;
      if (e < 100) {
        gp[e * 100 + l31] = acc0[r];
        gp[e * 100 + 32 + l31] = acc1[r];
        gp[e * 100 + 64 + l31] = acc2[r];
        if (l31 < 4) gp[e * 100 + 96 + l31] = acc3[r];
      }
    }
    cs += __shfl_xor(cs, 32);
    int row = wave * 32 + l31;
    if (lane < 32 && row < 100)
      CSp[((long)t * NBG + bx) * 100 + row] = cs;
  } else {
    // ---------------- k1-direct: Wm, in-block k-split x4 ----------------
    int bid2 = bid - 2 * NBG;
    int t = bid2 / K1B, eb = bid2 - t * K1B;
    const float* W = t ? W_im : W_re;
    const int efl = tid & 63, kg = tid >> 6;
    const int ef = eb * 64 + efl;
    for (int i = tid; i < 1600; i += 256) {
      int b = i / 100, k = i - b * 100;
      sm.k1.r2s[b][k] = R2[r_idx[b] * 100 + k];
    }
    __syncthreads();
    float acc[16];
#pragma unroll
    for (int b = 0; b < 16; b++) acc[b] = 0.f;
    if (ef < 10000) {
      const float* wp = W + (long)kg * 25 * 10000 + ef;
#pragma unroll 5
      for (int kk = 0; kk < 25; kk++) {
        float w = wp[kk * 10000];
        int k = kg * 25 + kk;
#pragma unroll
        for (int b = 0; b < 16; b++) acc[b] = fmaf(sm.k1.r2s[b][k], w, acc[b]);
      }
    }
#pragma unroll
    for (int b = 0; b < 16; b++) sm.k1.red[kg][efl][b] = acc[b];
    __syncthreads();
#pragma unroll
    for (int q = 0; q < 4; q++) {
      int o = tid + 256 * q;
      int b = o >> 6, efl2 = o & 63;
      int ef2 = eb * 64 + efl2;
      if (ef2 < 10000) {
        float s = sm.k1.red[0][efl2][b] + sm.k1.red[1][efl2][b] +
                  sm.k1.red[2][efl2][b] + sm.k1.red[3][efl2][b];
        Wm[t * 160000 + b * 10000 + ef2] = s;
      }
    }
  }
}

// ---------------------------------------------------------------------------
// L2: [k3a wide stage-A reduce 196->16 slices, 1280 blocks] ∥ [k4a traw, 32]
__global__ __launch_bounds__(256) void kB(const float* __restrict__ Gp,
                                          const float* __restrict__ CSp,
                                          float* __restrict__ Gp2,
                                          float* __restrict__ CSp2,
                                          const float* __restrict__ E_a,
                                          const float* __restrict__ E_b,
                                          const int* __restrict__ h_idx,
                                          const float* __restrict__ Wm,
                                          const float* __restrict__ g0r, const float* __restrict__ b0r,
                                          const float* __restrict__ g0i, const float* __restrict__ b0i,
                                          float* __restrict__ traw) {
  __shared__ float hrows[1600], x[100];
  const int bid = blockIdx.x, tid = threadIdx.x;
  if (bid < 40 * SLICES * 2) {
    int chunk = bid % 40, slice = (bid / 40) % SLICES, t = bid / (40 * SLICES);
    int nb0 = slice * SEG3;
    int nb1 = min(nb0 + SEG3, NBG);
    int idx = chunk * 256 + tid;
    if (idx < 10000) {
      float s = 0.f;
      const float* p = Gp + ((long)t * NBG + nb0) * 10000 + idx;
      for (int q = nb0; q < nb1; q++, p += 10000) s += *p;
      Gp2[(t * SLICES + slice) * 10000 + idx] = s;
    }
    if (chunk == 0 && tid < 100) {
      float s = 0.f;
      const float* p = CSp + ((long)t * NBG + nb0) * 100 + tid;
      for (int q = nb0; q < nb1; q++, p += 100) s += *p;
      CSp2[(t * SLICES + slice) * 100 + tid] = s;
    }
  } else {
    int bid2 = bid - 40 * SLICES * 2;
    int t = bid2 >> 4, b = bid2 & 15;
    const float4* E4 = (const float4*)(t ? E_b : E_a);
    const float* g0 = t ? g0i : g0r;
    const float* be0 = t ? b0i : b0r;
    for (int i = tid; i < 400; i += 256) {
      int b2 = i / 25, e4 = i - b2 * 25;
      float4 v = E4[(long)h_idx[b2] * 25 + e4];
      *(float4*)&hrows[b2 * 100 + e4 * 4] = v;
    }
    __syncthreads();
    if (tid < 100) {
      float m = 0.f, s = 0.f;
#pragma unroll
      for (int b2 = 0; b2 < 16; b2++) { float v = hrows[b2 * 100 + tid]; m += v; s += v * v; }
      m *= (1.f / 16.f);
      float var = s * (1.f / 16.f) - m * m;
      x[tid] = (hrows[b * 100 + tid] - m) * rsqrtf(var + EPS_F) * g0[tid] + be0[tid];
    }
    __syncthreads();
    if (tid < 100) {
      const float* W = Wm + t * 160000 + b * 10000 + tid;
      float s = 0.f;
#pragma unroll 4
      for (int e = 0; e < 100; e++) s = fmaf(x[e], W[e * 100], s);
      traw[t * 1600 + b * 100 + tid] = s;
    }
  }
}

// ---------------------------------------------------------------------------
// L3: kQF — quadratic forms with 16-deep L2-hot inline fold of Gp2/CSp2.
// grid 130 (cx 13 × ci 5 × t 2), block 128.
__global__ __launch_bounds__(128) void kQF(const float* __restrict__ Gp2,
                                           const float* __restrict__ CSp2,
                                           const float* __restrict__ Wm,
                                           float* __restrict__ qf,
                                           float* __restrict__ s2q) {
  const int bid = blockIdx.x;
  const int cx = bid % 13, ci = (bid / 13) % QCB, t = bid / (13 * QCB);
  const int tid = threadIdx.x;
  __shared__ __align__(16) float Gl[QCI][100];
  __shared__ float CSl[QCI];
  for (int i = tid; i < QCI * 100; i += 128) {
    int k = i / 100, e = i - k * 100;
    float s = 0.f;
    const float* p = Gp2 + (long)t * SLICES * 10000 + (ci * QCI + k) * 100 + e;
#pragma unroll
    for (int sl = 0; sl < SLICES; sl++) s += p[sl * 10000];
    Gl[k][e] = s;
  }
  if (tid < QCI) {
    float s = 0.f;
    const float* p = CSp2 + (long)t * SLICES * 100 + ci * QCI + tid;
#pragma unroll
    for (int sl = 0; sl < SLICES; sl++) s += p[sl * 100];
    CSl[tid] = s;
  }
  __syncthreads();
  int j = cx * 128 + tid;
  if (j >= 1600) return;
  int b = j / 100, f = j - b * 100;
  const float* Y = Wm + t * 160000 + b * 10000 + f;
  float yci[QCI];
  float cs2 = 0.f;
#pragma unroll
  for (int k = 0; k < QCI; k++) {
    yci[k] = Y[(ci * QCI + k) * 100];
    cs2 = fmaf(CSl[k], yci[k], cs2);
  }
  float acc = 0.f;
#pragma unroll 5
  for (int e4 = 0; e4 < 25; e4++) {
    float ye0 = Y[(e4 * 4 + 0) * 100];
    float ye1 = Y[(e4 * 4 + 1) * 100];
    float ye2 = Y[(e4 * 4 + 2) * 100];
    float ye3 = Y[(e4 * 4 + 3) * 100];
    float s0 = 0.f, s1 = 0.f, s2 = 0.f, s3 = 0.f;
#pragma unroll
    for (int k = 0; k < QCI; k++) {
      float4 g = *(const float4*)&Gl[k][e4 * 4];
      s0 = fmaf(g.x, yci[k], s0);
      s1 = fmaf(g.y, yci[k], s1);
      s2 = fmaf(g.z, yci[k], s2);
      s3 = fmaf(g.w, yci[k], s3);
    }
    acc += s0 * ye0 + s1 * ye1 + s2 * ye2 + s3 * ye3;
  }
  qf[((long)t * QCB + ci) * QNJ + j] = acc;
  s2q[((long)t * QCB + ci) * QNJ + j] = cs2;
}

// ---------------------------------------------------------------------------
// L4: kD — BN1 + Mobius + qf-fold + alpha/beta + c + u.  grid 32 × 256.
__global__ __launch_bounds__(256) void kD(const float* __restrict__ traw,
                                          const int* __restrict__ r_idx,
                                          const float* __restrict__ g1r, const float* __restrict__ b1r,
                                          const float* __restrict__ g1i, const float* __restrict__ b1i,
                                          const float* __restrict__ R_re, const float* __restrict__ R_im,
                                          const float* __restrict__ qf, const float* __restrict__ s2q,
                                          const float* __restrict__ gEa, const float* __restrict__ bEa,
                                          const float* __restrict__ gEb, const float* __restrict__ bEb,
                                          const float* __restrict__ Wm,
                                          float* __restrict__ u, float* __restrict__ c) {
  const int bid = blockIdx.x, tid = threadIdx.x;
  const int t2 = bid >> 4, bo = bid & 15;
  __shared__ float tr[3200], sca[200], shl[200], al[200], be[200];
  __shared__ float w0[100], w1[100], t01l[200], pc[128];
  __shared__ float Wl[10100];
  for (int i = tid; i < 3200; i += 256) tr[i] = traw[i];
  __syncthreads();
  if (tid < 200) {
    int tt = tid / 100, f = tid - tt * 100;
    float m = 0.f, s = 0.f;
#pragma unroll
    for (int b = 0; b < 16; b++) { float v = tr[tt * 1600 + b * 100 + f]; m += v; s += v * v; }
    m *= (1.f / 16.f);
    float var = s * (1.f / 16.f) - m * m;
    float g = tt ? g1i[f] : g1r[f];
    float bb = tt ? b1i[f] : b1r[f];
    float sc = rsqrtf(var + EPS_F) * g;
    sca[tid] = sc; shl[tid] = bb - m * sc;
    float s1 = 0.f, s2 = 0.f;
    const float* q = qf + (long)tt * QCB * QNJ + f;
    const float* z = s2q + (long)tt * QCB * QNJ + f;
#pragma unroll
    for (int ci = 0; ci < QCB; ci++) {
#pragma unroll
      for (int b2 = 0; b2 < 16; b2++) {
        s1 += q[ci * QNJ + b2 * 100];
        s2 += z[ci * QNJ + b2 * 100];
      }
    }
    float mean = s2 * (1.f / 800000.f);
    float var2 = s1 * (1.f / 800000.f) - mean * mean;
    float gE = tt ? gEb[f] : gEa[f];
    float bE = tt ? bEb[f] : bEa[f];
    float aa = rsqrtf(var2 + EPS_F) * gE;
    al[tid] = aa; be[tid] = bE - mean * aa;
  }
  __syncthreads();
  if (tid < 100) {
    int f = tid;
    float va = tr[bo * 100 + f] * sca[f] + shl[f];
    float vb = tr[1600 + bo * 100 + f] * sca[100 + f] + shl[100 + f];
    int base = r_idx[bo] * 400 + f;
    float ra0 = R_re[base],       ra1 = R_im[base];
    float rb0 = R_re[base + 100], rb1 = R_im[base + 100];
    float rc0 = R_re[base + 200], rc1 = R_im[base + 200];
    float rd0 = R_re[base + 300], rd1 = R_im[base + 300];
    float top0 = va * ra0 - vb * ra1 + rb0;
    float top1 = va * ra1 + vb * ra0 + rb1;
    float bot0 = va * rc0 - vb * rc1 + rd0;
    float bot1 = va * rc1 + vb * rc0 + rd1;
    float den = bot0 * bot0 + bot1 * bot1;
    float t0 = (top0 * bot0 + top1 * bot1) / den;
    float t1 = (top1 * bot0 - top0 * bot1) / den;
    t01l[f] = t0; t01l[100 + f] = t1;
    w0[f] = t0 * al[f];
    w1[f] = t1 * al[100 + f];
  }
  if (tid < 128) pc[tid] = 0.f;
  __syncthreads();
  if (tid < 100) pc[tid] = t01l[tid] * be[tid] + t01l[100 + tid] * be[100 + tid];
  __syncthreads();
  for (int o = 64; o > 0; o >>= 1) {
    if (tid < o) pc[tid] += pc[tid + o];
    __syncthreads();
  }
  if (tid == 0 && t2 == 0) c[bo] = pc[0];
  __syncthreads();
  {
    const float4* W4 = (const float4*)(Wm + t2 * 160000 + bo * 10000);
    for (int i = tid; i < 2500; i += 256) {
      float4 v = W4[i];
      int e = (i * 4) / 100, f0 = (i * 4) - e * 100;
      float* dst = &Wl[e * 101 + f0];
      dst[0] = v.x; dst[1] = v.y; dst[2] = v.z; dst[3] = v.w;
    }
    __syncthreads();
    if (tid < 100) {
      const float* row = &Wl[tid * 101];
      const float* w = t2 ? w1 : w0;
      float s = 0.f;
#pragma unroll 4
      for (int f = 0; f < 100; f++) s = fmaf(w[f], row[f], s);
      u[(t2 * 100 + tid) * 16 + bo] = s;
    }
  }
}

// ---------------------------------------------------------------------------
// L5: k9 split-t: block = 128 n × 2 tensors; 391 blocks.
__global__ __launch_bounds__(256) void k9_score(const float* __restrict__ E_a,
                                                const float* __restrict__ E_b,
                                                const float* __restrict__ u,
                                                const float* __restrict__ c,
                                                float* __restrict__ out) {
  __shared__ float ps[2][128][17];
  const int tid = threadIdx.x;
  const int t = tid >> 7, nl = tid & 127;
  const int n = blockIdx.x * 128 + nl;
  float acc[16];
#pragma unroll
  for (int b = 0; b < 16; b++) acc[b] = 0.f;
  if (n < NE) {
    const float4* Et4 = (const float4*)(t ? E_b : E_a);
    const float* ut = u + t * 1600;
    for (int e4 = 0; e4 < 25; e4++) {
      float4 v = Et4[(long)n * 25 + e4];
      const float* uu = ut + e4 * 64;
#pragma unroll
      for (int j = 0; j < 4; j++) {
        float fv = f4get(v, j);
#pragma unroll
        for (int b = 0; b < 16; b++)
          acc[b] = fmaf(uu[j * 16 + b], fv, acc[b]);
      }
    }
  }
#pragma unroll
  for (int b = 0; b < 16; b++) ps[t][nl][b] = acc[b];
  __syncthreads();
  if (tid < 128) {
    int n2 = blockIdx.x * 128 + tid;
    if (n2 < NE) {
#pragma unroll
      for (int b = 0; b < 16; b++) {
        float x = ps[0][tid][b] + ps[1][tid][b] + c[b];
        out[b * NE + n2] = 1.f / (1.f + expf(-x));
      }
    }
  }
}

// ---------------------------------------------------------------------------
extern "C" void kernel_launch(void* const* d_in, const int* in_sizes, int n_in,
                              void* d_out, int out_size, void* d_ws, size_t ws_size,
                              hipStream_t stream) {
  const int* h_idx = (const int*)d_in[0];
  const int* r_idx = (const int*)d_in[1];
  const float* E_a = (const float*)d_in[2];
  const float* E_b = (const float*)d_in[3];
  const float* R_re = (const float*)d_in[4];
  const float* R_im = (const float*)d_in[5];
  const float* R2 = (const float*)d_in[6];
  const float* W_re = (const float*)d_in[7];
  const float* W_im = (const float*)d_in[8];
  const float* g0r = (const float*)d_in[9];
  const float* b0r = (const float*)d_in[10];
  const float* g1r = (const float*)d_in[11];
  const float* b1r = (const float*)d_in[12];
  const float* g0i = (const float*)d_in[13];
  const float* b0i = (const float*)d_in[14];
  const float* g1i = (const float*)d_in[15];
  const float* b1i = (const float*)d_in[16];
  const float* gEa = (const float*)d_in[17];
  const float* bEa = (const float*)d_in[18];
  const float* gEb = (const float*)d_in[19];
  const float* bEb = (const float*)d_in[20];
  float* out = (float*)d_out;
  float* ws = (float*)d_ws;

  // layout (~4.65M floats ≈ 18.6 MB; ws is ~268 MB)
  float* Wm = ws;                    // [2][16][10000]     320000
  float* u = Wm + 320000;            // [2][100][16]         3200
  float* c = u + 3200;               //                        16
  float* qf = c + 16;                // [2][QCB][QNJ]       16640
  float* s2q = qf + 16640;           // [2][QCB][QNJ]       16640
  float* traw = s2q + 16640;         // [2][16][100]         3200
  float* Gp = traw + 3200;           // [2][NBG][10000]  3920000
  float* CSp = Gp + (long)2 * NBG * 10000;   // [2][NBG][100]  39200
  float* Gp2 = CSp + (long)2 * NBG * 100;    // [2][16][10000] 320000
  float* CSp2 = Gp2 + 320000;        // [2][16][100]         3200

  // L1: gram (392) ∥ k1-direct (314)
  hipLaunchKernelGGL(kA, dim3(2 * NBG + 2 * K1B), dim3(256), 0, stream,
                     W_re, W_im, R2, r_idx, E_a, E_b, Wm, Gp, CSp);
  // L2: k3a wide reduce (1280) ∥ k4a (32)
  hipLaunchKernelGGL(kB, dim3(40 * SLICES * 2 + 32), dim3(256), 0, stream,
                     Gp, CSp, Gp2, CSp2, E_a, E_b, h_idx, Wm,
                     g0r, b0r, g0i, b0i, traw);
  // L3: kQF with 16-deep fold (130)
  hipLaunchKernelGGL(kQF, dim3(13 * QCB * 2), dim3(128), 0, stream,
                     Gp2, CSp2, Wm, qf, s2q);
  // L4: kD (32)
  hipLaunchKernelGGL(kD, dim3(32), dim3(256), 0, stream, traw, r_idx,
                     g1r, b1r, g1i, b1i, R_re, R_im, qf, s2q,
                     gEa, bEa, gEb, bEb, Wm, u, c);
  // L5: k9 split-t (391)
  hipLaunchKernelGGL(k9_score, dim3((NE + 127) / 128), dim3(256), 0, stream,
                     E_a, E_b, u, c, out);
}

// Round 15
// 82.056 us; speedup vs baseline: 1.1676x; 1.1676x over previous
//
#include <hip/hip_runtime.h>
#include <math.h>

#define D100 100
#define NE 50000
#define BATCH 16
#define EPS_F 1e-5f
#define TPT 782              // 64-row tiles per tensor (782*64 = 50048, zero-padded)
#define TPB2 4               // tiles per gram block
#define NBG 196              // gram blocks per tensor (proven-fast width)
#define QCI 20               // e-rows per qf chunk
#define QCB 5                // chunks (100/QCI)
#define QNJ 1664             // padded column count
#define SLICES 16
#define SEG3 13              // ceil(NBG/SLICES)
#define K1B 157              // k1-direct ef-blocks per tensor

typedef __attribute__((ext_vector_type(8))) short short8;
typedef __attribute__((ext_vector_type(16))) float float16;
typedef unsigned short u16;
typedef unsigned int u32;

__device__ __forceinline__ float bf2f(u16 v) {
  return __uint_as_float(((u32)v) << 16);
}
__device__ __forceinline__ float f4get(const float4& v, int j) {
  switch (j) { case 0: return v.x; case 1: return v.y; case 2: return v.z; default: return v.w; }
}
__device__ __forceinline__ u32 cvt_pk_bf16(float lo, float hi) {
  u32 val;
  asm volatile("v_cvt_pk_bf16_f32 %0, %1, %2" : "=v"(val) : "v"(lo), "v"(hi));
  return val;
}

#define K2F_LOAD(tile)                                          \
    { int n0 = (tile) * 64;                                     \
      _Pragma("unroll")                                         \
      for (int s = 0; s < 4; s++) {                             \
        int i = s * 256 + tid;                                  \
        float4 a = make_float4(0.f, 0.f, 0.f, 0.f);             \
        float4 b = make_float4(0.f, 0.f, 0.f, 0.f);             \
        if (i < 800) {                                          \
          int p = i / 25, e4 = i - p * 25;                      \
          int n = n0 + 2 * p;                                   \
          if (n < NE)     a = E4[(long)n * 25 + e4];            \
          if (n + 1 < NE) b = E4[(long)(n + 1) * 25 + e4];      \
        }                                                       \
        st0[s] = a; st1[s] = b;                                 \
      } }

#define K2F_WRITE()                                             \
    { _Pragma("unroll")                                         \
      for (int s = 0; s < 4; s++) {                             \
        int i = s * 256 + tid;                                  \
        if (i < 800) {                                          \
          int p = i / 25, e4 = i - p * 25;                      \
          int ncl = p >> 3, half = (p >> 2) & 1, elem = 2 * (p & 3); \
          _Pragma("unroll")                                     \
          for (int j = 0; j < 4; j++) {                         \
            int e = e4 * 4 + j;                                 \
            u32 val = cvt_pk_bf16(f4get(st0[s], j), f4get(st1[s], j)); \
            FR32[((e >> 5) * 2048 + ncl * 512 + ((e & 31) + 32 * half) * 8 + elem) >> 1] = val; \
          } } } }

// ---------------------------------------------------------------------------
// L1: [k2f MFMA gram, 392 blocks] ∥ [k1-direct Wm build, 314 blocks]
__global__ __launch_bounds__(256) void kA(const float* __restrict__ W_re,
                                          const float* __restrict__ W_im,
                                          const float* __restrict__ R2,
                                          const int* __restrict__ r_idx,
                                          const float* __restrict__ E_a,
                                          const float* __restrict__ E_b,
                                          float* __restrict__ Wm,
                                          float* __restrict__ Gp,
                                          float* __restrict__ CSp) {
  __shared__ union {
    u16 fr[8192];                                              // gram tile (16 KB)
    struct { float r2s[16][100]; float red[4][64][17]; } k1;   // 23.8 KB
  } sm;
  const int bid = blockIdx.x, tid = threadIdx.x;

  if (bid < 2 * NBG) {
    // ---------------- k2f: fused transpose+cast+MFMA Gram ----------------
    const int t = bid / NBG, bx = bid - t * NBG;
    const float4* E4 = (const float4*)(t ? E_b : E_a);
    u16* FR = sm.fr;
    u32* FR32 = (u32*)sm.fr;
    const int wave = tid >> 6, lane = tid & 63, l31 = lane & 31;

    for (int i = tid; i < 4096; i += 256) FR32[i] = 0;   // rows e>=100 stay 0

    const int ti0 = bx * TPB2;
    const int nt = min(ti0 + TPB2, TPT) - ti0;

    float16 acc0, acc1, acc2, acc3;
#pragma unroll 16
    for (int r = 0; r < 16; r++) { acc0[r] = 0.f; acc1[r] = 0.f; acc2[r] = 0.f; acc3[r] = 0.f; }
    float cs = 0.f;
    float4 st0[4], st1[4];

    __syncthreads();
    K2F_LOAD(ti0);
    K2F_WRITE();
    __syncthreads();

    for (int tt = 0; tt < nt; tt++) {
      if (tt + 1 < nt) K2F_LOAD(ti0 + tt + 1);
#pragma unroll
      for (int ncl = 0; ncl < 4; ncl++) {
        const u16* pf = FR + ncl * 512 + lane * 8;
        short8 f0 = *(const short8*)pf;
        short8 f1 = *(const short8*)(pf + 2048);
        short8 f2 = *(const short8*)(pf + 4096);
        short8 f3 = *(const short8*)(pf + 6144);
        short8 av = *(const short8*)(pf + wave * 2048);
        acc0 = __builtin_amdgcn_mfma_f32_32x32x16_bf16(av, f0, acc0, 0, 0, 0);
        acc1 = __builtin_amdgcn_mfma_f32_32x32x16_bf16(av, f1, acc1, 0, 0, 0);
        acc2 = __builtin_amdgcn_mfma_f32_32x32x16_bf16(av, f2, acc2, 0, 0, 0);
        acc3 = __builtin_amdgcn_mfma_f32_32x32x16_bf16(av, f3, acc3, 0, 0, 0);
#pragma unroll
        for (int j = 0; j < 8; j++) cs += bf2f((u16)av[j]);
      }
      __syncthreads();
      if (tt + 1 < nt) {
        K2F_WRITE();
        __syncthreads();
      }
    }

    float* gp = Gp + ((long)t * NBG + bx) * 10000;
#pragma unroll 16
    for (int r = 0; r < 16; r++) {
      int m = (r & 3) + 8 * (r >> 2) + 4 * (lane >> 5);   // verified C/D mapping
      int e = wave * 32 + m;
      if (e < 100) {
        gp[e * 100 + l31] = acc0[r];
        gp[e * 100 + 32 + l31] = acc1[r];
        gp[e * 100 + 64 + l31] = acc2[r];
        if (l31 < 4) gp[e * 100 + 96 + l31] = acc3[r];
      }
    }
    cs += __shfl_xor(cs, 32);
    int row = wave * 32 + l31;
    if (lane < 32 && row < 100)
      CSp[((long)t * NBG + bx) * 100 + row] = cs;
  } else {
    // ---------------- k1-direct: Wm, in-block k-split x4 ----------------
    int bid2 = bid - 2 * NBG;
    int t = bid2 / K1B, eb = bid2 - t * K1B;
    const float* W = t ? W_im : W_re;
    const int efl = tid & 63, kg = tid >> 6;
    const int ef = eb * 64 + efl;
    for (int i = tid; i < 1600; i += 256) {
      int b = i / 100, k = i - b * 100;
      sm.k1.r2s[b][k] = R2[r_idx[b] * 100 + k];
    }
    __syncthreads();
    float acc[16];
#pragma unroll
    for (int b = 0; b < 16; b++) acc[b] = 0.f;
    if (ef < 10000) {
      const float* wp = W + (long)kg * 25 * 10000 + ef;
#pragma unroll 5
      for (int kk = 0; kk < 25; kk++) {
        float w = wp[kk * 10000];
        int k = kg * 25 + kk;
#pragma unroll
        for (int b = 0; b < 16; b++) acc[b] = fmaf(sm.k1.r2s[b][k], w, acc[b]);
      }
    }
#pragma unroll
    for (int b = 0; b < 16; b++) sm.k1.red[kg][efl][b] = acc[b];
    __syncthreads();
#pragma unroll
    for (int q = 0; q < 4; q++) {
      int o = tid + 256 * q;
      int b = o >> 6, efl2 = o & 63;
      int ef2 = eb * 64 + efl2;
      if (ef2 < 10000) {
        float s = sm.k1.red[0][efl2][b] + sm.k1.red[1][efl2][b] +
                  sm.k1.red[2][efl2][b] + sm.k1.red[3][efl2][b];
        Wm[t * 160000 + b * 10000 + ef2] = s;
      }
    }
  }
}

// ---------------------------------------------------------------------------
// L2: [k3a wide stage-A reduce 196->16 slices, 1280 blocks] ∥ [k4a traw, 32]
__global__ __launch_bounds__(256) void kB(const float* __restrict__ Gp,
                                          const float* __restrict__ CSp,
                                          float* __restrict__ Gp2,
                                          float* __restrict__ CSp2,
                                          const float* __restrict__ E_a,
                                          const float* __restrict__ E_b,
                                          const int* __restrict__ h_idx,
                                          const float* __restrict__ Wm,
                                          const float* __restrict__ g0r, const float* __restrict__ b0r,
                                          const float* __restrict__ g0i, const float* __restrict__ b0i,
                                          float* __restrict__ traw) {
  __shared__ float hrows[1600], x[100];
  const int bid = blockIdx.x, tid = threadIdx.x;
  if (bid < 40 * SLICES * 2) {
    int chunk = bid % 40, slice = (bid / 40) % SLICES, t = bid / (40 * SLICES);
    int nb0 = slice * SEG3;
    int nb1 = min(nb0 + SEG3, NBG);
    int idx = chunk * 256 + tid;
    if (idx < 10000) {
      float s = 0.f;
      const float* p = Gp + ((long)t * NBG + nb0) * 10000 + idx;
      for (int q = nb0; q < nb1; q++, p += 10000) s += *p;
      Gp2[(t * SLICES + slice) * 10000 + idx] = s;
    }
    if (chunk == 0 && tid < 100) {
      float s = 0.f;
      const float* p = CSp + ((long)t * NBG + nb0) * 100 + tid;
      for (int q = nb0; q < nb1; q++, p += 100) s += *p;
      CSp2[(t * SLICES + slice) * 100 + tid] = s;
    }
  } else {
    int bid2 = bid - 40 * SLICES * 2;
    int t = bid2 >> 4, b = bid2 & 15;
    const float4* E4 = (const float4*)(t ? E_b : E_a);
    const float* g0 = t ? g0i : g0r;
    const float* be0 = t ? b0i : b0r;
    for (int i = tid; i < 400; i += 256) {
      int b2 = i / 25, e4 = i - b2 * 25;
      float4 v = E4[(long)h_idx[b2] * 25 + e4];
      *(float4*)&hrows[b2 * 100 + e4 * 4] = v;
    }
    __syncthreads();
    if (tid < 100) {
      float m = 0.f, s = 0.f;
#pragma unroll
      for (int b2 = 0; b2 < 16; b2++) { float v = hrows[b2 * 100 + tid]; m += v; s += v * v; }
      m *= (1.f / 16.f);
      float var = s * (1.f / 16.f) - m * m;
      x[tid] = (hrows[b * 100 + tid] - m) * rsqrtf(var + EPS_F) * g0[tid] + be0[tid];
    }
    __syncthreads();
    if (tid < 100) {
      const float* W = Wm + t * 160000 + b * 10000 + tid;
      float s = 0.f;
#pragma unroll 4
      for (int e = 0; e < 100; e++) s = fmaf(x[e], W[e * 100], s);
      traw[t * 1600 + b * 100 + tid] = s;
    }
  }
}

// ---------------------------------------------------------------------------
// L3: kQF — quadratic forms with 16-deep L2-hot inline fold of Gp2/CSp2.
// grid 130 (cx 13 × ci 5 × t 2), block 128.
__global__ __launch_bounds__(128) void kQF(const float* __restrict__ Gp2,
                                           const float* __restrict__ CSp2,
                                           const float* __restrict__ Wm,
                                           float* __restrict__ qf,
                                           float* __restrict__ s2q) {
  const int bid = blockIdx.x;
  const int cx = bid % 13, ci = (bid / 13) % QCB, t = bid / (13 * QCB);
  const int tid = threadIdx.x;
  __shared__ __align__(16) float Gl[QCI][100];
  __shared__ float CSl[QCI];
  for (int i = tid; i < QCI * 100; i += 128) {
    int k = i / 100, e = i - k * 100;
    float s = 0.f;
    const float* p = Gp2 + (long)t * SLICES * 10000 + (ci * QCI + k) * 100 + e;
#pragma unroll
    for (int sl = 0; sl < SLICES; sl++) s += p[sl * 10000];
    Gl[k][e] = s;
  }
  if (tid < QCI) {
    float s = 0.f;
    const float* p = CSp2 + (long)t * SLICES * 100 + ci * QCI + tid;
#pragma unroll
    for (int sl = 0; sl < SLICES; sl++) s += p[sl * 100];
    CSl[tid] = s;
  }
  __syncthreads();
  int j = cx * 128 + tid;
  if (j >= 1600) return;
  int b = j / 100, f = j - b * 100;
  const float* Y = Wm + t * 160000 + b * 10000 + f;
  float yci[QCI];
  float cs2 = 0.f;
#pragma unroll
  for (int k = 0; k < QCI; k++) {
    yci[k] = Y[(ci * QCI + k) * 100];
    cs2 = fmaf(CSl[k], yci[k], cs2);
  }
  float acc = 0.f;
#pragma unroll 5
  for (int e4 = 0; e4 < 25; e4++) {
    float ye0 = Y[(e4 * 4 + 0) * 100];
    float ye1 = Y[(e4 * 4 + 1) * 100];
    float ye2 = Y[(e4 * 4 + 2) * 100];
    float ye3 = Y[(e4 * 4 + 3) * 100];
    float s0 = 0.f, s1 = 0.f, s2 = 0.f, s3 = 0.f;
#pragma unroll
    for (int k = 0; k < QCI; k++) {
      float4 g = *(const float4*)&Gl[k][e4 * 4];
      s0 = fmaf(g.x, yci[k], s0);
      s1 = fmaf(g.y, yci[k], s1);
      s2 = fmaf(g.z, yci[k], s2);
      s3 = fmaf(g.w, yci[k], s3);
    }
    acc += s0 * ye0 + s1 * ye1 + s2 * ye2 + s3 * ye3;
  }
  qf[((long)t * QCB + ci) * QNJ + j] = acc;
  s2q[((long)t * QCB + ci) * QNJ + j] = cs2;
}

// ---------------------------------------------------------------------------
// L4: kD — BN1 + Mobius + qf-fold + alpha/beta + c + u.  grid 32 × 256.
__global__ __launch_bounds__(256) void kD(const float* __restrict__ traw,
                                          const int* __restrict__ r_idx,
                                          const float* __restrict__ g1r, const float* __restrict__ b1r,
                                          const float* __restrict__ g1i, const float* __restrict__ b1i,
                                          const float* __restrict__ R_re, const float* __restrict__ R_im,
                                          const float* __restrict__ qf, const float* __restrict__ s2q,
                                          const float* __restrict__ gEa, const float* __restrict__ bEa,
                                          const float* __restrict__ gEb, const float* __restrict__ bEb,
                                          const float* __restrict__ Wm,
                                          float* __restrict__ u, float* __restrict__ c) {
  const int bid = blockIdx.x, tid = threadIdx.x;
  const int t2 = bid >> 4, bo = bid & 15;
  __shared__ float tr[3200], sca[200], shl[200], al[200], be[200];
  __shared__ float w0[100], w1[100], t01l[200], pc[128];
  __shared__ float Wl[10100];
  for (int i = tid; i < 3200; i += 256) tr[i] = traw[i];
  __syncthreads();
  if (tid < 200) {
    int tt = tid / 100, f = tid - tt * 100;
    float m = 0.f, s = 0.f;
#pragma unroll
    for (int b = 0; b < 16; b++) { float v = tr[tt * 1600 + b * 100 + f]; m += v; s += v * v; }
    m *= (1.f / 16.f);
    float var = s * (1.f / 16.f) - m * m;
    float g = tt ? g1i[f] : g1r[f];
    float bb = tt ? b1i[f] : b1r[f];
    float sc = rsqrtf(var + EPS_F) * g;
    sca[tid] = sc; shl[tid] = bb - m * sc;
    float s1 = 0.f, s2 = 0.f;
    const float* q = qf + (long)tt * QCB * QNJ + f;
    const float* z = s2q + (long)tt * QCB * QNJ + f;
#pragma unroll
    for (int ci = 0; ci < QCB; ci++) {
#pragma unroll
      for (int b2 = 0; b2 < 16; b2++) {
        s1 += q[ci * QNJ + b2 * 100];
        s2 += z[ci * QNJ + b2 * 100];
      }
    }
    float mean = s2 * (1.f / 800000.f);
    float var2 = s1 * (1.f / 800000.f) - mean * mean;
    float gE = tt ? gEb[f] : gEa[f];
    float bE = tt ? bEb[f] : bEa[f];
    float aa = rsqrtf(var2 + EPS_F) * gE;
    al[tid] = aa; be[tid] = bE - mean * aa;
  }
  __syncthreads();
  if (tid < 100) {
    int f = tid;
    float va = tr[bo * 100 + f] * sca[f] + shl[f];
    float vb = tr[1600 + bo * 100 + f] * sca[100 + f] + shl[100 + f];
    int base = r_idx[bo] * 400 + f;
    float ra0 = R_re[base],       ra1 = R_im[base];
    float rb0 = R_re[base + 100], rb1 = R_im[base + 100];
    float rc0 = R_re[base + 200], rc1 = R_im[base + 200];
    float rd0 = R_re[base + 300], rd1 = R_im[base + 300];
    float top0 = va * ra0 - vb * ra1 + rb0;
    float top1 = va * ra1 + vb * ra0 + rb1;
    float bot0 = va * rc0 - vb * rc1 + rd0;
    float bot1 = va * rc1 + vb * rc0 + rd1;
    float den = bot0 * bot0 + bot1 * bot1;
    float t0 = (top0 * bot0 + top1 * bot1) / den;
    float t1 = (top1 * bot0 - top0 * bot1) / den;
    t01l[f] = t0; t01l[100 + f] = t1;
    w0[f] = t0 * al[f];
    w1[f] = t1 * al[100 + f];
  }
  if (tid < 128) pc[tid] = 0.f;
  __syncthreads();
  if (tid < 100) pc[tid] = t01l[tid] * be[tid] + t01l[100 + tid] * be[100 + tid];
  __syncthreads();
  for (int o = 64; o > 0; o >>= 1) {
    if (tid < o) pc[tid] += pc[tid + o];
    __syncthreads();
  }
  if (tid == 0 && t2 == 0) c[bo] = pc[0];
  __syncthreads();
  {
    const float4* W4 = (const float4*)(Wm + t2 * 160000 + bo * 10000);
    for (int i = tid; i < 2500; i += 256) {
      float4 v = W4[i];
      int e = (i * 4) / 100, f0 = (i * 4) - e * 100;
      float* dst = &Wl[e * 101 + f0];
      dst[0] = v.x; dst[1] = v.y; dst[2] = v.z; dst[3] = v.w;
    }
    __syncthreads();
    if (tid < 100) {
      const float* row = &Wl[tid * 101];
      const float* w = t2 ? w1 : w0;
      float s = 0.f;
#pragma unroll 4
      for (int f = 0; f < 100; f++) s = fmaf(w[f], row[f], s);
      u[(t2 * 100 + tid) * 16 + bo] = s;
    }
  }
}

// ---------------------------------------------------------------------------
// L5: k9 score = sigmoid(c + u_a·E_a + u_b·E_b).  grid 196 × 256
__global__ __launch_bounds__(256) void k9_score(const float* __restrict__ E_a,
                                                const float* __restrict__ E_b,
                                                const float* __restrict__ u,
                                                const float* __restrict__ c,
                                                float* __restrict__ out) {
  int n = blockIdx.x * 256 + threadIdx.x;
  if (n >= NE) return;
  const float4* Ea4 = (const float4*)E_a;
  const float4* Eb4 = (const float4*)E_b;
  float acc[16];
#pragma unroll
  for (int b = 0; b < 16; b++) acc[b] = 0.f;
  for (int e4 = 0; e4 < 25; e4++) {
    float4 va = Ea4[n * 25 + e4];
    float4 vb = Eb4[n * 25 + e4];
    const float* ua = u + e4 * 64;
    const float* ub = u + 1600 + e4 * 64;
#pragma unroll
    for (int j = 0; j < 4; j++) {
      float fa = f4get(va, j);
      float fb = f4get(vb, j);
#pragma unroll
      for (int b = 0; b < 16; b++) {
        acc[b] = fmaf(ua[j * 16 + b], fa, acc[b]);
        acc[b] = fmaf(ub[j * 16 + b], fb, acc[b]);
      }
    }
  }
#pragma unroll
  for (int b = 0; b < 16; b++) {
    float x = acc[b] + c[b];
    out[b * NE + n] = 1.f / (1.f + expf(-x));
  }
}

// ---------------------------------------------------------------------------
extern "C" void kernel_launch(void* const* d_in, const int* in_sizes, int n_in,
                              void* d_out, int out_size, void* d_ws, size_t ws_size,
                              hipStream_t stream) {
  const int* h_idx = (const int*)d_in[0];
  const int* r_idx = (const int*)d_in[1];
  const float* E_a = (const float*)d_in[2];
  const float* E_b = (const float*)d_in[3];
  const float* R_re = (const float*)d_in[4];
  const float* R_im = (const float*)d_in[5];
  const float* R2 = (const float*)d_in[6];
  const float* W_re = (const float*)d_in[7];
  const float* W_im = (const float*)d_in[8];
  const float* g0r = (const float*)d_in[9];
  const float* b0r = (const float*)d_in[10];
  const float* g1r = (const float*)d_in[11];
  const float* b1r = (const float*)d_in[12];
  const float* g0i = (const float*)d_in[13];
  const float* b0i = (const float*)d_in[14];
  const float* g1i = (const float*)d_in[15];
  const float* b1i = (const float*)d_in[16];
  const float* gEa = (const float*)d_in[17];
  const float* bEa = (const float*)d_in[18];
  const float* gEb = (const float*)d_in[19];
  const float* bEb = (const float*)d_in[20];
  float* out = (float*)d_out;
  float* ws = (float*)d_ws;

  // layout (~4.65M floats ≈ 18.6 MB; ws is ~268 MB)
  float* Wm = ws;                    // [2][16][10000]     320000
  float* u = Wm + 320000;            // [2][100][16]         3200
  float* c = u + 3200;               //                        16
  float* qf = c + 16;                // [2][QCB][QNJ]       16640
  float* s2q = qf + 16640;           // [2][QCB][QNJ]       16640
  float* traw = s2q + 16640;         // [2][16][100]         3200
  float* Gp = traw + 3200;           // [2][NBG][10000]  3920000
  float* CSp = Gp + (long)2 * NBG * 10000;   // [2][NBG][100]  39200
  float* Gp2 = CSp + (long)2 * NBG * 100;    // [2][16][10000] 320000
  float* CSp2 = Gp2 + 320000;        // [2][16][100]         3200

  // L1: gram (392) ∥ k1-direct (314)
  hipLaunchKernelGGL(kA, dim3(2 * NBG + 2 * K1B), dim3(256), 0, stream,
                     W_re, W_im, R2, r_idx, E_a, E_b, Wm, Gp, CSp);
  // L2: k3a wide reduce (1280) ∥ k4a (32)
  hipLaunchKernelGGL(kB, dim3(40 * SLICES * 2 + 32), dim3(256), 0, stream,
                     Gp, CSp, Gp2, CSp2, E_a, E_b, h_idx, Wm,
                     g0r, b0r, g0i, b0i, traw);
  // L3: kQF with 16-deep fold (130)
  hipLaunchKernelGGL(kQF, dim3(13 * QCB * 2), dim3(128), 0, stream,
                     Gp2, CSp2, Wm, qf, s2q);
  // L4: kD (32)
  hipLaunchKernelGGL(kD, dim3(32), dim3(256), 0, stream, traw, r_idx,
                     g1r, b1r, g1i, b1i, R_re, R_im, qf, s2q,
                     gEa, bEa, gEb, bEb, Wm, u, c);
  // L5: k9 (196)
  hipLaunchKernelGGL(k9_score, dim3((NE + 255) / 256), dim3(256), 0, stream,
                     E_a, E_b, u, c, out);
}